// Round 4
// baseline (141.522 us; speedup 1.0000x reference)
//
#include <hip/hip_runtime.h>

#define IMG_H 480
#define IMG_W 640
#define OUT_H 470    // 480 - 10
#define OUT_W 630    // 640 - 10
#define NBATCH 32
#define SW 126       // output columns per wave (63 lanes x 2); 5*126 = 630 exact
#define NSTRIPE 5
#define RCH 23       // output rows per wave-chunk (21*23 = 483 >= 470, tail masked)
#define NCHUNK 21
#define WPB 3        // waves per block (independent row-chunks, no sync; 21 = 7*3)
#define NROWS (RCH + 10)   // 33 input rows per chunk = one 33-step literal body

#define SSIM_C1 1.0f // (0.01*100)^2
#define SSIM_C2 9.0f // (0.03*100)^2

typedef float v2f __attribute__((ext_vector_type(2)));

// Normalized 11-tap Gaussian (sigma=1.5), matches numpy fp32 window to ~1e-7 rel.
__device__ constexpr float WG[11] = {
    0.00102838f, 0.00759876f, 0.03600077f, 0.10936068f, 0.21300554f,
    0.26601173f,
    0.21300554f, 0.10936068f, 0.03600077f, 0.00759876f, 0.00102838f
};

// Packed fp32 fma: llvm.fma.v2f32 -> v_pk_fma_f32 (2 FLOP-pairs per issue slot)
__device__ __forceinline__ v2f pk_fma(v2f a, v2f b, v2f c) {
    return __builtin_elementwise_fma(a, b, c);
}

// One phase. R3 lesson: 1-step prefetch distance (~420 issue-cycles) < L3/HBM
// load latency (~500-900 cyc) -> every wave stalled ~50% on vmcnt; VALUBusy
// pinned at ~44% across ALL tilings. Fix: 3-buffer ring, prefetch row IT+2,
// giving ~840 cycles of slack. pb index = PP%3 -> unroll length must be a
// multiple of 33 (mod 11 for ring phase AND mod 3 for buffers): one 33-step
// fully-literal body, no tail.
// *** INDEXING MUST BE COMPILE-TIME *** PP is a post-unroll literal.
// IT used only for addresses / wave-uniform bounds (runtime OK).
// REGISTER BUDGET: R1/R3 landed 112 VGPR (2-buf). +1 row buffer = +24 regs
// -> expect ~130-140. Sentinel: WRITE_SIZE must stay ~70 KB (no scratch) --
// R2 proved a spill shows up as WRITE_SIZE ~118 MB and a 5x regression.
#define STEP(IT, PP)                                                          \
  {                                                                           \
    const int P   = (PP) % 11;                                                \
    const int cur = (PP) % 3;                                                 \
    const int nx2 = ((PP) + 2) % 3;                                           \
    /* 1. VMEM prefetch row IT+2 into pb[nx2] (clamped; tail overshoot ok) */ \
    {                                                                         \
      int gy = y0 + (IT) + 2; if (gy > IMG_H - 1) gy = IMG_H - 1;             \
      const float* __restrict__ r1 = p1 + gy * IMG_W + colA;                  \
      const float* __restrict__ r2 = p2 + gy * IMG_W + colA;                  \
      _Pragma("unroll")                                                       \
      for (int k = 0; k < 6; ++k) {                                           \
        pb[nx2][0][k] = *(const v2f*)(r1 + 2 * k);                            \
        pb[nx2][1][k] = *(const v2f*)(r2 + 2 * k);                            \
      }                                                                       \
    }                                                                         \
    /* 2. h-pass on pb[cur] (row IT, loaded 2 steps ago), packed over (A,B) */\
    v2f h1  = (v2f){0.f,0.f}, h2  = (v2f){0.f,0.f};                           \
    v2f h11 = (v2f){0.f,0.f}, h22 = (v2f){0.f,0.f}, h12 = (v2f){0.f,0.f};     \
    _Pragma("unroll")                                                         \
    for (int j = 0; j < 11; ++j) {                                            \
      const v2f wj = (v2f){WG[j], WG[j]};                                     \
      v2f q1, q2;                                                             \
      if (j & 1) {                                                            \
        q1 = (v2f){pb[cur][0][j >> 1].y, pb[cur][0][(j >> 1) + 1].x};         \
        q2 = (v2f){pb[cur][1][j >> 1].y, pb[cur][1][(j >> 1) + 1].x};         \
      } else {                                                                \
        q1 = pb[cur][0][j >> 1];                                              \
        q2 = pb[cur][1][j >> 1];                                              \
      }                                                                       \
      const v2f t1 = wj * q1;                                                 \
      const v2f t2 = wj * q2;                                                 \
      h1 += t1; h2 += t2;                                                     \
      h11 = pk_fma(t1, q1, h11);                                              \
      h22 = pk_fma(t2, q2, h22);                                              \
      h12 = pk_fma(t1, q2, h12);                                              \
    }                                                                         \
    /* 3. vertical ring update: 5 pk_fma per slot */                          \
    _Pragma("unroll")                                                         \
    for (int sl = 0; sl < 11; ++sl) {                                         \
      const float wt = WG[(P - sl + 11) % 11];                                \
      const v2f wv = (v2f){wt, wt};                                           \
      acc[sl][0] = pk_fma(wv, h1,  acc[sl][0]);                               \
      acc[sl][1] = pk_fma(wv, h2,  acc[sl][1]);                               \
      acc[sl][2] = pk_fma(wv, h11, acc[sl][2]);                               \
      acc[sl][3] = pk_fma(wv, h22, acc[sl][3]);                               \
      acc[sl][4] = pk_fma(wv, h12, acc[sl][4]);                               \
    }                                                                         \
    /* 4. slot sc got its w[10] tap -> output row y = IT-10 completes */      \
    const int sc = (P + 1) % 11;                                              \
    if ((IT) >= 10 && (y0 + (IT) - 10) < OUT_H) {                             \
      const v2f m1 = acc[sc][0], m2 = acc[sc][1];                             \
      const v2f msq1 = m1 * m1, msq2 = m2 * m2, mu12 = m1 * m2;               \
      const v2f two = (v2f){2.f, 2.f};                                        \
      const v2f c1v = (v2f){SSIM_C1, SSIM_C1};                                \
      const v2f c2v = (v2f){SSIM_C2, SSIM_C2};                                \
      const v2f vA = pk_fma(two, acc[sc][4] - mu12, c2v);                     \
      const v2f vB = (acc[sc][2] - msq1) + (acc[sc][3] - msq2) + c2v;         \
      const v2f num = pk_fma(two, mu12, c1v) * vA;                            \
      const v2f den = (msq1 + msq2 + c1v) * vB;                               \
      if (validA) lsum = fmaf(num.x, __builtin_amdgcn_rcpf(den.x), lsum);     \
      if (validB) lsum = fmaf(num.y, __builtin_amdgcn_rcpf(den.y), lsum);     \
    }                                                                         \
    _Pragma("unroll")                                                         \
    for (int ch = 0; ch < 5; ++ch) acc[sc][ch] = (v2f){0.f, 0.f};             \
  }

__global__ __launch_bounds__(64 * WPB, 2) void ssim_main(
    const float* __restrict__ img1,
    const float* __restrict__ img2,
    float* __restrict__ partials)
{
    const int lane   = threadIdx.x & 63;
    const int wv     = threadIdx.x >> 6;          // wave id in block, 0..2
    const int stripe = blockIdx.x;
    const int cy     = blockIdx.y * WPB + wv;     // 0..20
    const int b      = blockIdx.z;
    const int x0 = SW * stripe;
    const int y0 = RCH * cy;

    const float* __restrict__ p1 = img1 + (size_t)b * (IMG_H * IMG_W);
    const float* __restrict__ p2 = img2 + (size_t)b * (IMG_H * IMG_W);

    // lane's 12-col window base; clamp keeps cols colA..colA+11 in-bounds.
    // Any VALID output col c needs window c..c+10 with base c <= 628, so the
    // clamp is a no-op for valid lanes (it only moves invalid/edge lanes).
    int colA = x0 + 2 * lane;
    if (colA > IMG_W - 12) colA = IMG_W - 12;   // 628, even -> 8B aligned

    // lane l produces output cols x0+2l (A) and x0+2l+1 (B); with SW=126
    // exactly lanes 0..62 are valid (5*126 = 630, no stripe overlap waste)
    const bool validA = (2 * lane     < SW) && (x0 + 2 * lane     < OUT_W);
    const bool validB = (2 * lane + 1 < SW) && (x0 + 2 * lane + 1 < OUT_W);

    // vertical ring: 5 channels (mu1, mu2, s11, s22, s12), each v2f over (A,B)
    v2f acc[11][5];
#pragma unroll
    for (int i = 0; i < 11; ++i)
#pragma unroll
        for (int ch = 0; ch < 5; ++ch) acc[i][ch] = (v2f){0.f, 0.f};

    float lsum = 0.f;

    // input-row ring: pb[mod3][image][pair 0..5], prefetch distance 2
    v2f pb[3][2][6];

    // prologue: rows y0, y0+1 -> pb[0], pb[1]
#pragma unroll
    for (int r = 0; r < 2; ++r) {
        const float* __restrict__ r1 = p1 + (y0 + r) * IMG_W + colA;
        const float* __restrict__ r2 = p2 + (y0 + r) * IMG_W + colA;
#pragma unroll
        for (int k = 0; k < 6; ++k) {
            pb[r][0][k] = *(const v2f*)(r1 + 2 * k);
            pb[r][1][k] = *(const v2f*)(r2 + 2 * k);
        }
    }

    // 33 rows: single fully-literal unroll (33 ≡ 0 mod 11 and mod 3 -> ring
    // phase P and buffer index PP%3 fold to literals for every step).
#pragma unroll
    for (int p = 0; p < 33; ++p) STEP(p, p)

    // per-wave reduction (shfl is wave-scoped, 64 lanes)
#pragma unroll
    for (int off = 32; off > 0; off >>= 1)
        lsum += __shfl_down(lsum, off);
    if (lane == 0)
        partials[(b * NCHUNK + cy) * NSTRIPE + stripe] = lsum;
}

__global__ __launch_bounds__(256) void ssim_reduce(
    const float* __restrict__ partials, float* __restrict__ out)
{
    const int n = NSTRIPE * NCHUNK * NBATCH;  // 3360
    __shared__ double red[256];
    int tid = threadIdx.x;
    double s = 0.0;
    for (int i = tid; i < n; i += 256) s += (double)partials[i];
    red[tid] = s;
    __syncthreads();
    for (int k = 128; k > 0; k >>= 1) {
        if (tid < k) red[tid] += red[tid + k];
        __syncthreads();
    }
    if (tid == 0) {
        double mean = red[0] / (double)((size_t)NBATCH * OUT_H * OUT_W);
        out[0] = (float)((1.0 - mean) * 0.5);
    }
}

extern "C" void kernel_launch(void* const* d_in, const int* in_sizes, int n_in,
                              void* d_out, int out_size, void* d_ws, size_t ws_size,
                              hipStream_t stream)
{
    const float* img1 = (const float*)d_in[0];
    const float* img2 = (const float*)d_in[1];
    float* out = (float*)d_out;
    float* partials = (float*)d_ws;  // 3360 floats = 13.4 KB

    // 5 x 7 x 32 = 1120 blocks x 3 waves = 3360 waves
    dim3 grid(NSTRIPE, NCHUNK / WPB, NBATCH);
    ssim_main<<<grid, dim3(64 * WPB), 0, stream>>>(img1, img2, partials);
    ssim_reduce<<<1, dim3(256), 0, stream>>>(partials, out);
}

// Round 5
// 135.391 us; speedup vs baseline: 1.0453x; 1.0453x over previous
//
#include <hip/hip_runtime.h>

#define IMG_H 480
#define IMG_W 640
#define OUT_H 470    // 480 - 10
#define OUT_W 630    // 640 - 10
#define NBATCH 32
#define SW 126       // output columns per wave (63 lanes x 2); 5*126 = 630 exact
#define NSTRIPE 5
#define RCH 34       // output rows per wave-chunk (14*34 = 476 >= 470, tail masked)
#define NCHUNK 14
#define WPB 2        // waves per block (independent row-chunks, no sync; 14 = 2*7)
#define NROWS (RCH + 10)   // 44 input rows = 2 x 22-step loop, no tail

#define SSIM_C1 1.0f // (0.01*100)^2
#define SSIM_C2 9.0f // (0.03*100)^2

typedef float v2f __attribute__((ext_vector_type(2)));

// Normalized 11-tap Gaussian (sigma=1.5), matches numpy fp32 window to ~1e-7 rel.
__device__ constexpr float WG[11] = {
    0.00102838f, 0.00759876f, 0.03600077f, 0.10936068f, 0.21300554f,
    0.26601173f,
    0.21300554f, 0.10936068f, 0.03600077f, 0.00759876f, 0.00102838f
};

// Packed fp32 fma: llvm.fma.v2f32 -> v_pk_fma_f32 (2 FLOP-pairs per issue slot)
__device__ __forceinline__ v2f pk_fma(v2f a, v2f b, v2f c) {
    return __builtin_elementwise_fma(a, b, c);
}

// One phase. HISTORY: R1/R3 (2-buf, straight-line 34 steps) = 57.4us, VALU 44%.
// R4 (3-buf, prefetch dist 2) = 64.9us, VALU 38% -> load-latency theory
// falsified; compiler already hoists loads in straight-line code. R5 theory:
// the ~45KB fully-unrolled body exceeds 32KB L1I and streams from L2 once per
// wave -> I-fetch pins duty cycle at ~42%. Fix: 22-step body (~28KB, fits
// L1I) looped twice via "#pragma unroll 1" -> 2nd iteration hits L1I.
// 22 ≡ 0 mod 11 and even -> ring phase P = p%11 and parity p&1 fold to
// literals with ANY even runtime base (base = 22*blk).
// *** INDEXING MUST BE COMPILE-TIME *** PP is a post-unroll literal.
// IT (runtime base + literal) used only for addresses / wave-uniform bounds.
// REGISTER BUDGET: 2-buffer proven at 112 VGPR, no spill, launch_bounds(_,2).
// Sentinels: VGPR ~112, WRITE_SIZE ~70 KB (R2 proved spill = 118 MB + 5x).
#define STEP(IT, PP)                                                          \
  {                                                                           \
    const int P   = (PP) % 11;                                                \
    const int cur = (PP) & 1;                                                 \
    const int nxt = ((PP) + 1) & 1;                                           \
    /* 1. VMEM prefetch row IT+1 into pb[nxt] (clamped; tail overshoot ok) */ \
    {                                                                         \
      int gy = y0 + (IT) + 1; if (gy > IMG_H - 1) gy = IMG_H - 1;             \
      const float* __restrict__ r1 = p1 + gy * IMG_W + colA;                  \
      const float* __restrict__ r2 = p2 + gy * IMG_W + colA;                  \
      _Pragma("unroll")                                                       \
      for (int k = 0; k < 6; ++k) {                                           \
        pb[nxt][0][k] = *(const v2f*)(r1 + 2 * k);                            \
        pb[nxt][1][k] = *(const v2f*)(r2 + 2 * k);                            \
      }                                                                       \
    }                                                                         \
    /* 2. h-pass on pb[cur] (row IT), packed over output cols (A,B) */        \
    v2f h1  = (v2f){0.f,0.f}, h2  = (v2f){0.f,0.f};                           \
    v2f h11 = (v2f){0.f,0.f}, h22 = (v2f){0.f,0.f}, h12 = (v2f){0.f,0.f};     \
    _Pragma("unroll")                                                         \
    for (int j = 0; j < 11; ++j) {                                            \
      const v2f wj = (v2f){WG[j], WG[j]};                                     \
      v2f q1, q2;                                                             \
      if (j & 1) {                                                            \
        q1 = (v2f){pb[cur][0][j >> 1].y, pb[cur][0][(j >> 1) + 1].x};         \
        q2 = (v2f){pb[cur][1][j >> 1].y, pb[cur][1][(j >> 1) + 1].x};         \
      } else {                                                                \
        q1 = pb[cur][0][j >> 1];                                              \
        q2 = pb[cur][1][j >> 1];                                              \
      }                                                                       \
      const v2f t1 = wj * q1;                                                 \
      const v2f t2 = wj * q2;                                                 \
      h1 += t1; h2 += t2;                                                     \
      h11 = pk_fma(t1, q1, h11);                                              \
      h22 = pk_fma(t2, q2, h22);                                              \
      h12 = pk_fma(t1, q2, h12);                                              \
    }                                                                         \
    /* 3. vertical ring update: 5 pk_fma per slot */                          \
    _Pragma("unroll")                                                         \
    for (int sl = 0; sl < 11; ++sl) {                                         \
      const float wt = WG[(P - sl + 11) % 11];                                \
      const v2f wv = (v2f){wt, wt};                                           \
      acc[sl][0] = pk_fma(wv, h1,  acc[sl][0]);                               \
      acc[sl][1] = pk_fma(wv, h2,  acc[sl][1]);                               \
      acc[sl][2] = pk_fma(wv, h11, acc[sl][2]);                               \
      acc[sl][3] = pk_fma(wv, h22, acc[sl][3]);                               \
      acc[sl][4] = pk_fma(wv, h12, acc[sl][4]);                               \
    }                                                                         \
    /* 4. slot sc got its w[10] tap -> output row y = IT-10 completes */      \
    const int sc = (P + 1) % 11;                                              \
    if ((IT) >= 10 && (y0 + (IT) - 10) < OUT_H) {                             \
      const v2f m1 = acc[sc][0], m2 = acc[sc][1];                             \
      const v2f msq1 = m1 * m1, msq2 = m2 * m2, mu12 = m1 * m2;               \
      const v2f two = (v2f){2.f, 2.f};                                        \
      const v2f c1v = (v2f){SSIM_C1, SSIM_C1};                                \
      const v2f c2v = (v2f){SSIM_C2, SSIM_C2};                                \
      const v2f vA = pk_fma(two, acc[sc][4] - mu12, c2v);                     \
      const v2f vB = (acc[sc][2] - msq1) + (acc[sc][3] - msq2) + c2v;         \
      const v2f num = pk_fma(two, mu12, c1v) * vA;                            \
      const v2f den = (msq1 + msq2 + c1v) * vB;                               \
      if (validA) lsum = fmaf(num.x, __builtin_amdgcn_rcpf(den.x), lsum);     \
      if (validB) lsum = fmaf(num.y, __builtin_amdgcn_rcpf(den.y), lsum);     \
    }                                                                         \
    _Pragma("unroll")                                                         \
    for (int ch = 0; ch < 5; ++ch) acc[sc][ch] = (v2f){0.f, 0.f};             \
  }

__global__ __launch_bounds__(64 * WPB, 2) void ssim_main(
    const float* __restrict__ img1,
    const float* __restrict__ img2,
    float* __restrict__ partials)
{
    const int lane   = threadIdx.x & 63;
    const int wv     = threadIdx.x >> 6;          // wave id in block, 0..1
    const int stripe = blockIdx.x;
    const int cy     = blockIdx.y * WPB + wv;     // 0..13
    const int b      = blockIdx.z;
    const int x0 = SW * stripe;
    const int y0 = RCH * cy;

    const float* __restrict__ p1 = img1 + (size_t)b * (IMG_H * IMG_W);
    const float* __restrict__ p2 = img2 + (size_t)b * (IMG_H * IMG_W);

    // lane's 12-col window base; clamp keeps cols colA..colA+11 in-bounds.
    // Any VALID output col c needs window c..c+10 with base c <= 628, so the
    // clamp is a no-op for valid lanes (it only moves invalid/edge lanes).
    int colA = x0 + 2 * lane;
    if (colA > IMG_W - 12) colA = IMG_W - 12;   // 628, even -> 8B aligned

    // lane l produces output cols x0+2l (A) and x0+2l+1 (B); with SW=126
    // exactly lanes 0..62 are valid (5*126 = 630, no stripe overlap waste)
    const bool validA = (2 * lane     < SW) && (x0 + 2 * lane     < OUT_W);
    const bool validB = (2 * lane + 1 < SW) && (x0 + 2 * lane + 1 < OUT_W);

    // vertical ring: 5 channels (mu1, mu2, s11, s22, s12), each v2f over (A,B)
    v2f acc[11][5];
#pragma unroll
    for (int i = 0; i < 11; ++i)
#pragma unroll
        for (int ch = 0; ch < 5; ++ch) acc[i][ch] = (v2f){0.f, 0.f};

    float lsum = 0.f;

    // input-row ping-pong: pb[parity][image][pair 0..5]
    v2f pb[2][2][6];

    // prologue: row 0 -> pb[0]
    {
        const float* __restrict__ r1 = p1 + y0 * IMG_W + colA;
        const float* __restrict__ r2 = p2 + y0 * IMG_W + colA;
#pragma unroll
        for (int k = 0; k < 6; ++k) {
            pb[0][0][k] = *(const v2f*)(r1 + 2 * k);
            pb[0][1][k] = *(const v2f*)(r2 + 2 * k);
        }
    }

    // 44 rows = 2 iterations of a 22-step body. "#pragma unroll 1" keeps the
    // outer loop ROLLED so the ~28KB body fits L1I and iteration 2 hits cache.
#pragma unroll 1
    for (int blk = 0; blk < 2; ++blk) {
        const int base = 22 * blk;
#pragma unroll
        for (int p = 0; p < 22; ++p) STEP(base + p, p)
    }

    // per-wave reduction (shfl is wave-scoped, 64 lanes)
#pragma unroll
    for (int off = 32; off > 0; off >>= 1)
        lsum += __shfl_down(lsum, off);
    if (lane == 0)
        partials[(b * NCHUNK + cy) * NSTRIPE + stripe] = lsum;
}

__global__ __launch_bounds__(256) void ssim_reduce(
    const float* __restrict__ partials, float* __restrict__ out)
{
    const int n = NSTRIPE * NCHUNK * NBATCH;  // 2240
    __shared__ double red[256];
    int tid = threadIdx.x;
    double s = 0.0;
    for (int i = tid; i < n; i += 256) s += (double)partials[i];
    red[tid] = s;
    __syncthreads();
    for (int k = 128; k > 0; k >>= 1) {
        if (tid < k) red[tid] += red[tid + k];
        __syncthreads();
    }
    if (tid == 0) {
        double mean = red[0] / (double)((size_t)NBATCH * OUT_H * OUT_W);
        out[0] = (float)((1.0 - mean) * 0.5);
    }
}

extern "C" void kernel_launch(void* const* d_in, const int* in_sizes, int n_in,
                              void* d_out, int out_size, void* d_ws, size_t ws_size,
                              hipStream_t stream)
{
    const float* img1 = (const float*)d_in[0];
    const float* img2 = (const float*)d_in[1];
    float* out = (float*)d_out;
    float* partials = (float*)d_ws;  // 2240 floats = 9.0 KB

    // 5 x 7 x 32 = 1120 blocks x 2 waves = 2240 waves
    dim3 grid(NSTRIPE, NCHUNK / WPB, NBATCH);
    ssim_main<<<grid, dim3(64 * WPB), 0, stream>>>(img1, img2, partials);
    ssim_reduce<<<1, dim3(256), 0, stream>>>(partials, out);
}